// Round 1
// baseline (403.244 us; speedup 1.0000x reference)
//
#include <hip/hip_runtime.h>

typedef float    f4v    __attribute__((ext_vector_type(4)));
typedef __bf16   bf16x8 __attribute__((ext_vector_type(8)));
typedef __bf16   bf16x4 __attribute__((ext_vector_type(4)));

#define NPAIR 32896   // 256*257/2, = 257*128
#define CH 1024
#define K1 2048
#define LSEQ 256

__device__ __forceinline__ int tri_off(int x) { return (x * (513 - x)) >> 1; }

// ---------------- small prep kernels ----------------

__global__ void k_sum(const int* am, int* sbuf) {
    __shared__ int sh[256];
    int t = threadIdx.x;
    sh[t] = am[t];
    __syncthreads();
    for (int d = 128; d; d >>= 1) { if (t < d) sh[t] += sh[t + d]; __syncthreads(); }
    if (t == 0) sbuf[0] = sh[0];
}

__global__ void k_pairs(int* pi, int* pj) {
    int idx = blockIdx.x * 256 + threadIdx.x;
    if (idx >= NPAIR) return;
    float disc = 263169.0f - 8.0f * (float)idx;
    int i = (int)floorf((513.0f - sqrtf(disc)) * 0.5f);
    i = min(255, max(0, i));
    while (i > 0 && tri_off(i) > idx) --i;
    while (tri_off(i + 1) <= idx) ++i;
    pi[idx] = i;
    pj[idx] = i + (idx - tri_off(i));
}

__global__ void k_maskz(const float* att, const int* am, const int* sbuf, float* z) {
    int l = blockIdx.x;
    int s = sbuf[0];
    float m = (l != 0 && l != s && am[l] != 0) ? 1.0f : 0.0f;
    int c = threadIdx.x * 4;
    float4 v = *(const float4*)&att[l * CH + c];
    v.x *= m; v.y *= m; v.z *= m; v.w *= m;
    *(float4*)&z[l * CH + c] = v;
}

__global__ void k_cvtA(const float* w, __bf16* o) {
    size_t e = ((size_t)blockIdx.x * 256 + threadIdx.x) * 8;
    float4 a = *(const float4*)&w[e];
    float4 b = *(const float4*)&w[e + 4];
    bf16x8 v;
    v[0] = (__bf16)a.x; v[1] = (__bf16)a.y; v[2] = (__bf16)a.z; v[3] = (__bf16)a.w;
    v[4] = (__bf16)b.x; v[5] = (__bf16)b.y; v[6] = (__bf16)b.z; v[7] = (__bf16)b.w;
    *(bf16x8*)&o[e] = v;
}

// K2[t][o] = conv2_w[0][o][di][dj] with t = di*7+dj (t<49), rows 49..127 zero
__global__ void k_prepK2(const float* c2w, __bf16* K2) {
    int e = blockIdx.x * 256 + threadIdx.x;   // 128*1024 elements
    int t = e >> 10, o = e & 1023;
    K2[e] = (t < 49) ? (__bf16)c2w[o * 49 + t] : (__bf16)0.0f;
}

// one wave per output row: dot(pooled, W[o]) + b[o]
__global__ void k_gemv(const float* x, const float* w, const float* b, float* y) {
    int o = blockIdx.x * 4 + (threadIdx.x >> 6);
    int lane = threadIdx.x & 63;
    const float* row = w + (size_t)o * CH;
    float s = 0.f;
    for (int c = lane; c < CH; c += 64) s += x[c] * row[c];
    for (int d = 32; d; d >>= 1) s += __shfl_down(s, d);
    if (lane == 0) y[o] = s + b[o];
}

// featT[n][k] (bf16, row stride 2048): k<1024 -> |z[k,i]-z[k,j]|, k>=1024 -> z*z
__global__ void k_feat(const float* z, const int* pi, const int* pj, __bf16* featT) {
    int t = threadIdx.x;
    bool ismul = (t >= 128);
    int c = (ismul ? (t - 128) : t) * 8;
    for (int q = 0; q < 8; q++) {
        int n = blockIdx.x * 8 + q;
        int i = pi[n], j = pj[n];
        const float* zi = &z[i * CH + c];
        const float* zj = &z[j * CH + c];
        float4 a0 = *(const float4*)zi, a1 = *(const float4*)(zi + 4);
        float4 b0 = *(const float4*)zj, b1 = *(const float4*)(zj + 4);
        float va[8] = {a0.x, a0.y, a0.z, a0.w, a1.x, a1.y, a1.z, a1.w};
        float vb[8] = {b0.x, b0.y, b0.z, b0.w, b1.x, b1.y, b1.z, b1.w};
        bf16x8 ov;
#pragma unroll
        for (int r = 0; r < 8; r++) {
            float v = ismul ? (va[r] * vb[r]) : fabsf(va[r] - vb[r]);
            ov[r] = (__bf16)v;
        }
        *(bf16x8*)&featT[(size_t)n * K1 + t * 8] = ov;
    }
}

// ---------------- MFMA GEMM (m97-style): D[m][n] = sum_k A[m][k]*B[n][k]^T ----------------
// A: [Mtiles*128][K] bf16 row-major (lda=K), B: [N][K] bf16 row-major (ldb=K, i.e. B^T)
// mode 0: hT[n][1024+o] = bf16(relu(acc + bias[o]))     (GEMM1)
// mode 1: Q[t][NPAIR+n] = acc for t<49                    (GEMM2)
__global__ __launch_bounds__(256) void gemm_bt(const __bf16* __restrict__ A,
                                               const __bf16* __restrict__ B,
                                               int K, int lda, int ldb, int mode,
                                               const float* __restrict__ bias,
                                               __bf16* __restrict__ hT,
                                               float* __restrict__ Q) {
    __shared__ __bf16 As[128][32];
    __shared__ __bf16 Bs[128][32];
    int tid = threadIdx.x, wave = tid >> 6, lane = tid & 63;
    int mb = blockIdx.x, nb = blockIdx.y;
    int rin = lane >> 2, cin = lane & 3;

    const __bf16* src[4];
    __bf16* dst[4];
#pragma unroll
    for (int q = 0; q < 4; q++) {
        int g = wave * 4 + q;
        if (g < 8) {
            src[q] = A + (size_t)(mb * 128 + g * 16 + rin) * lda + cin * 8;
            dst[q] = &As[g * 16][0];
        } else {
            int gg = g - 8;
            src[q] = B + (size_t)(nb * 128 + gg * 16 + rin) * ldb + cin * 8;
            dst[q] = &Bs[gg * 16][0];
        }
    }

    f4v acc[4][4] = {};
    int row16 = lane & 15, quad = lane >> 4;
    int wx = wave & 1, wy = wave >> 1;
    int kiters = K / 32;

    for (int kt = 0; kt < kiters; ++kt) {
#pragma unroll
        for (int q = 0; q < 4; q++) {
            __builtin_amdgcn_global_load_lds(
                (const __attribute__((address_space(1))) void*)src[q],
                (__attribute__((address_space(3))) void*)dst[q], 16, 0, 0);
            src[q] += 32;
        }
        __syncthreads();
        bf16x8 a[4], b[4];
#pragma unroll
        for (int mt = 0; mt < 4; mt++) a[mt] = *(const bf16x8*)&As[wy * 64 + mt * 16 + row16][quad * 8];
#pragma unroll
        for (int nt = 0; nt < 4; nt++) b[nt] = *(const bf16x8*)&Bs[wx * 64 + nt * 16 + row16][quad * 8];
#pragma unroll
        for (int mt = 0; mt < 4; mt++)
#pragma unroll
            for (int nt = 0; nt < 4; nt++)
                acc[mt][nt] = __builtin_amdgcn_mfma_f32_16x16x32_bf16(a[mt], b[nt], acc[mt][nt], 0, 0, 0);
        __syncthreads();
    }

    if (mode == 0) {
#pragma unroll
        for (int mt = 0; mt < 4; mt++) {
            int o = mb * 128 + wy * 64 + mt * 16 + quad * 4;
            float4 bv = *(const float4*)&bias[o];
#pragma unroll
            for (int nt = 0; nt < 4; nt++) {
                int n = nb * 128 + wx * 64 + nt * 16 + row16;
                bf16x4 pk;
                pk[0] = (__bf16)fmaxf(acc[mt][nt][0] + bv.x, 0.f);
                pk[1] = (__bf16)fmaxf(acc[mt][nt][1] + bv.y, 0.f);
                pk[2] = (__bf16)fmaxf(acc[mt][nt][2] + bv.z, 0.f);
                pk[3] = (__bf16)fmaxf(acc[mt][nt][3] + bv.w, 0.f);
                *(bf16x4*)&hT[(size_t)n * CH + o] = pk;
            }
        }
    } else {
#pragma unroll
        for (int mt = 0; mt < 4; mt++) {
            int t0 = wy * 64 + mt * 16 + quad * 4;
#pragma unroll
            for (int nt = 0; nt < 4; nt++) {
                int n = nb * 128 + wx * 64 + nt * 16 + row16;
#pragma unroll
                for (int r = 0; r < 4; r++)
                    if (t0 + r < 49) Q[(size_t)(t0 + r) * NPAIR + n] = acc[mt][nt][r];
            }
        }
    }
}

// out[i,j] = sigmoid(b2 + sum_taps Q[t][pidx(sorted(i+di-3, j+dj-3))]), mirrored
__global__ void k_out(const float* __restrict__ Q, const int* pi, const int* pj,
                      const float* b2, float* __restrict__ outmaps) {
    int idx = blockIdx.x * 256 + threadIdx.x;
    if (idx >= NPAIR) return;
    int i = pi[idx], j = pj[idx];
    float acc = b2[0];
    for (int di = 0; di < 7; di++) {
        int p = i + di - 3;
        if ((unsigned)p > 255u) continue;
        for (int dj = 0; dj < 7; dj++) {
            int q = j + dj - 3;
            if ((unsigned)q > 255u) continue;
            int a = p, b = q;
            if (a > b) { a = q; b = p; }
            int n2 = tri_off(a) + (b - a);
            acc += Q[(size_t)(di * 7 + dj) * NPAIR + n2];
        }
    }
    float sg = 1.0f / (1.0f + expf(-acc));
    outmaps[i * 256 + j] = sg;
    outmaps[j * 256 + i] = sg;
}

// ---------------- launch ----------------

extern "C" void kernel_launch(void* const* d_in, const int* in_sizes, int n_in,
                              void* d_out, int out_size, void* d_ws, size_t ws_size,
                              hipStream_t stream) {
    const float* att    = (const float*)d_in[0];
    const float* pooled = (const float*)d_in[1];
    const int*   am     = (const int*)d_in[2];
    const float* lin1_w = (const float*)d_in[3];
    const float* lin1_b = (const float*)d_in[4];
    const float* cls_w  = (const float*)d_in[5];
    const float* cls_b  = (const float*)d_in[6];
    const float* c1w    = (const float*)d_in[7];
    const float* c1b    = (const float*)d_in[8];
    const float* c2w    = (const float*)d_in[9];
    const float* c2b    = (const float*)d_in[10];
    float* out = (float*)d_out;
    char*  ws  = (char*)d_ws;

    // workspace layout (all 256B aligned); total ~214.4 MB
    __bf16* featT = (__bf16*)(ws);                    // 32896*2048*2 = 134,742,016
    __bf16* hT    = (__bf16*)(ws + 134742016);        // 32896*1024*2 =  67,371,008
    float*  Q     = (float*) (ws + 202113024);        // 49*32896*4   =   6,447,616
    __bf16* A1    = (__bf16*)(ws + 208560640);        // 1024*2048*2  =   4,194,304
    __bf16* K2    = (__bf16*)(ws + 212754944);        // 128*1024*2   =     262,144
    float*  z     = (float*) (ws + 213017088);        // 256*1024*4   =   1,048,576
    int*    pi    = (int*)   (ws + 214065664);        // 32896*4
    int*    pj    = (int*)   (ws + 214197248);        // 32896*4
    float*  hid   = (float*) (ws + 214328832);        // 1024*4
    int*    sbuf  = (int*)   (ws + 214332928);

    k_sum   <<<1,   256, 0, stream>>>(am, sbuf);
    k_pairs <<<129, 256, 0, stream>>>(pi, pj);
    k_maskz <<<256, 256, 0, stream>>>(att, am, sbuf, z);
    k_cvtA  <<<1024,256, 0, stream>>>(c1w, A1);
    k_prepK2<<<512, 256, 0, stream>>>(c2w, K2);
    k_gemv  <<<256, 256, 0, stream>>>(pooled, lin1_w, lin1_b, hid);   // hidden[1024]
    k_gemv  <<<500, 256, 0, stream>>>(hid, cls_w, cls_b, out);        // logits[2000]
    k_feat  <<<4112,256, 0, stream>>>(z, pi, pj, featT);

    gemm_bt <<<dim3(8, 257),   256, 0, stream>>>(A1, featT, K1, K1, K1, 0, c1b, hT, nullptr);
    gemm_bt <<<dim3(1, 257),   256, 0, stream>>>(K2, hT, CH, CH, CH, 1, nullptr, nullptr, Q);

    k_out   <<<129, 256, 0, stream>>>(Q, pi, pj, c2b, out + 2000);
}

// Round 2
// 249.149 us; speedup vs baseline: 1.6185x; 1.6185x over previous
//
#include <hip/hip_runtime.h>

typedef float    f4v    __attribute__((ext_vector_type(4)));
typedef __bf16   bf16x8 __attribute__((ext_vector_type(8)));
typedef __bf16   bf16x4 __attribute__((ext_vector_type(4)));

#define NPAIR 32896   // 256*257/2 (full-position tri count, used by k_out grid)
#define PCAP  32512   // max padded active-pair count (A<=254 -> P<=32385 -> pad 32512)
#define LDQ   32512
#define CH 1024
#define K1 2048

__device__ __forceinline__ int tri_off(int x) { return (x * (513 - x)) >> 1; }      // full 256 tri
__device__ __forceinline__ int offA(int r, int A) { return r * A - ((r * (r - 1)) >> 1); }

// ---------------- prep: mask scan -> rank/active/counts ----------------
__global__ void k_scan(const int* am, int* rank, int* active, int* counts) {
    __shared__ int red[256];
    __shared__ int scan[256];
    int t = threadIdx.x;
    int a = am[t];
    red[t] = a; __syncthreads();
    for (int d = 128; d; d >>= 1) { if (t < d) red[t] += red[t + d]; __syncthreads(); }
    int s = red[0]; __syncthreads();
    int keep = (t != 0 && t != s && a != 0) ? 1 : 0;
    scan[t] = keep; __syncthreads();
    for (int d = 1; d < 256; d <<= 1) {
        int v = (t >= d) ? scan[t - d] : 0;
        __syncthreads();
        scan[t] += v;
        __syncthreads();
    }
    int incl = scan[t], excl = incl - keep;
    rank[t] = keep ? excl : -1;
    if (keep) active[excl] = t;
    if (t == 255) {
        int A = incl;
        int P = (A * (A + 1)) >> 1;
        counts[0] = A; counts[1] = P; counts[2] = ((P + 127) >> 7) << 7;
    }
}

// active-pair list: pi/pj positions for packed upper-tri over active ranks
__global__ void k_pairs(const int* active, const int* counts, int* pi, int* pj) {
    int idx = blockIdx.x * 256 + threadIdx.x;
    int A = counts[0], P = counts[1];
    if (idx >= P || A <= 0) return;
    float fA = (float)(2 * A + 1);
    float disc = fmaxf(fA * fA - 8.0f * (float)idx, 0.0f);
    int r = (int)floorf((fA - sqrtf(disc)) * 0.5f);
    r = min(A - 1, max(0, r));
    while (r > 0 && offA(r, A) > idx) --r;
    while (r < A - 1 && offA(r + 1, A) <= idx) ++r;
    int rj = r + (idx - offA(r, A));
    pi[idx] = active[r];
    pj[idx] = active[rj];
}

// z (masked, fp32) + |z| bf16 transposed-free copy
__global__ void k_maskz(const float* att, const int* rank, float* z, __bf16* absZ) {
    int l = blockIdx.x;
    float m = (rank[l] >= 0) ? 1.0f : 0.0f;
    int c = threadIdx.x * 4;
    float4 v = *(const float4*)&att[l * CH + c];
    v.x *= m; v.y *= m; v.z *= m; v.w *= m;
    *(float4*)&z[l * CH + c] = v;
    bf16x4 av;
    av[0] = (__bf16)fabsf(v.x); av[1] = (__bf16)fabsf(v.y);
    av[2] = (__bf16)fabsf(v.z); av[3] = (__bf16)fabsf(v.w);
    *(bf16x4*)&absZ[l * CH + c] = av;
}

__global__ void k_cvtA(const float* w, __bf16* o) {
    size_t e = ((size_t)blockIdx.x * 256 + threadIdx.x) * 8;
    float4 a = *(const float4*)&w[e];
    float4 b = *(const float4*)&w[e + 4];
    bf16x8 v;
    v[0] = (__bf16)a.x; v[1] = (__bf16)a.y; v[2] = (__bf16)a.z; v[3] = (__bf16)a.w;
    v[4] = (__bf16)b.x; v[5] = (__bf16)b.y; v[6] = (__bf16)b.z; v[7] = (__bf16)b.w;
    *(bf16x8*)&o[e] = v;
}

// K2[t][o] = conv2_w[o][t], t=di*7+dj (t<49), rows 49..127 zero
__global__ void k_prepK2(const float* c2w, __bf16* K2) {
    int e = blockIdx.x * 256 + threadIdx.x;   // 128*1024
    int t = e >> 10, o = e & 1023;
    K2[e] = (t < 49) ? (__bf16)c2w[o * 49 + t] : (__bf16)0.0f;
}

// Qc[t] = sum_o conv2_w[o][t] * relu(c1b[o])
__global__ void k_qconst(const float* c2w, const float* b1, float* Qc) {
    __shared__ float sh[256];
    int t = blockIdx.x, tid = threadIdx.x;
    float s = 0.f;
    for (int o = tid; o < CH; o += 256) s += c2w[o * 49 + t] * fmaxf(b1[o], 0.f);
    sh[tid] = s; __syncthreads();
    for (int d = 128; d; d >>= 1) { if (tid < d) sh[tid] += sh[tid + d]; __syncthreads(); }
    if (tid == 0) Qc[t] = sh[0];
}

__global__ void k_zeroQ(float* Q, float* Qs) {
    int idx = blockIdx.x * 256 + threadIdx.x;   // 401408 float4 total
    float4 zv = {0.f, 0.f, 0.f, 0.f};
    if (idx < 398272) ((float4*)Q)[idx];        // touch nothing extra
    if (idx < 398272) ((float4*)Q)[idx] = zv;
    else ((float4*)Qs)[idx - 398272] = zv;      // 3136 float4 = 49*256
}

// one wave per output row: dot(x, w[o]) + b[o]
__global__ void k_gemv(const float* x, const float* w, const float* b, float* y) {
    int o = blockIdx.x * 4 + (threadIdx.x >> 6);
    int lane = threadIdx.x & 63;
    const float* row = w + (size_t)o * CH;
    float s = 0.f;
    for (int c = lane; c < CH; c += 64) s += x[c] * row[c];
    for (int d = 32; d; d >>= 1) s += __shfl_down(s, d);
    if (lane == 0) y[o] = s + b[o];
}

// featT[n][k]: k<1024 -> |z[k,i]-z[k,j]|, k>=1024 -> z*z ; rows [P,Ppad) zeroed
__global__ void k_feat(const float* z, const int* pi, const int* pj,
                       const int* counts, __bf16* featT) {
    int P = counts[1], Ppad = counts[2];
    int n0 = blockIdx.x * 8;
    if (n0 >= Ppad) return;
    int t = threadIdx.x;
    bool ismul = (t >= 128);
    int c = (ismul ? (t - 128) : t) * 8;
    for (int q = 0; q < 8; q++) {
        int n = n0 + q;
        bf16x8 ov;
        if (n < P) {
            int i = pi[n], j = pj[n];
            const float* zi = &z[i * CH + c];
            const float* zj = &z[j * CH + c];
            float4 a0 = *(const float4*)zi, a1 = *(const float4*)(zi + 4);
            float4 b0 = *(const float4*)zj, b1 = *(const float4*)(zj + 4);
            float va[8] = {a0.x, a0.y, a0.z, a0.w, a1.x, a1.y, a1.z, a1.w};
            float vb[8] = {b0.x, b0.y, b0.z, b0.w, b1.x, b1.y, b1.z, b1.w};
#pragma unroll
            for (int r = 0; r < 8; r++) {
                float v = ismul ? (va[r] * vb[r]) : fabsf(va[r] - vb[r]);
                ov[r] = (__bf16)v;
            }
        } else {
#pragma unroll
            for (int r = 0; r < 8; r++) ov[r] = (__bf16)0.0f;
        }
        *(bf16x8*)&featT[(size_t)n * K1 + t * 8] = ov;
    }
}

// ---------------- MFMA GEMM: D[m][n] = sum_k A[m][k]*B[n][k] ----------------
// mode 0: hT[n*CH + o] = bf16(relu(acc + bias[o]))
// mode 2: split-K (blockIdx.x = k-chunk of 256): atomicAdd Q[t*ldq + n] for t<49
__global__ __launch_bounds__(256) void gemm_bt(const __bf16* __restrict__ A,
                                               const __bf16* __restrict__ B,
                                               int K, int lda, int ldb, int mode, int ldq,
                                               const int* __restrict__ nlimit,
                                               const float* __restrict__ bias,
                                               __bf16* __restrict__ hT,
                                               float* __restrict__ Q) {
    int mb = blockIdx.x, nb = blockIdx.y;
    if (nlimit && nb * 128 >= nlimit[0]) return;
    if (mode == 2) { A += (size_t)blockIdx.x * 256; B += (size_t)blockIdx.x * 256; mb = 0; }

    __shared__ __bf16 As[128][32];
    __shared__ __bf16 Bs[128][32];
    int tid = threadIdx.x, wave = tid >> 6, lane = tid & 63;
    int rin = lane >> 2, cin = lane & 3;

    const __bf16* src[4];
    __bf16* dst[4];
#pragma unroll
    for (int q = 0; q < 4; q++) {
        int g = wave * 4 + q;
        if (g < 8) {
            src[q] = A + (size_t)(mb * 128 + g * 16 + rin) * lda + cin * 8;
            dst[q] = &As[g * 16][0];
        } else {
            int gg = g - 8;
            src[q] = B + (size_t)(nb * 128 + gg * 16 + rin) * ldb + cin * 8;
            dst[q] = &Bs[gg * 16][0];
        }
    }

    f4v acc[4][4] = {};
    int row16 = lane & 15, quad = lane >> 4;
    int wx = wave & 1, wy = wave >> 1;
    int kiters = K / 32;

    for (int kt = 0; kt < kiters; ++kt) {
#pragma unroll
        for (int q = 0; q < 4; q++) {
            __builtin_amdgcn_global_load_lds(
                (const __attribute__((address_space(1))) void*)src[q],
                (__attribute__((address_space(3))) void*)dst[q], 16, 0, 0);
            src[q] += 32;
        }
        __syncthreads();
        bf16x8 a[4], b[4];
#pragma unroll
        for (int mt = 0; mt < 4; mt++) a[mt] = *(const bf16x8*)&As[wy * 64 + mt * 16 + row16][quad * 8];
#pragma unroll
        for (int nt = 0; nt < 4; nt++) b[nt] = *(const bf16x8*)&Bs[wx * 64 + nt * 16 + row16][quad * 8];
#pragma unroll
        for (int mt = 0; mt < 4; mt++)
#pragma unroll
            for (int nt = 0; nt < 4; nt++)
                acc[mt][nt] = __builtin_amdgcn_mfma_f32_16x16x32_bf16(a[mt], b[nt], acc[mt][nt], 0, 0, 0);
        __syncthreads();
    }

    if (mode == 0) {
#pragma unroll
        for (int mt = 0; mt < 4; mt++) {
            int o = mb * 128 + wy * 64 + mt * 16 + quad * 4;
            float4 bv = *(const float4*)&bias[o];
#pragma unroll
            for (int nt = 0; nt < 4; nt++) {
                int n = nb * 128 + wx * 64 + nt * 16 + row16;
                bf16x4 pk;
                pk[0] = (__bf16)fmaxf(acc[mt][nt][0] + bv.x, 0.f);
                pk[1] = (__bf16)fmaxf(acc[mt][nt][1] + bv.y, 0.f);
                pk[2] = (__bf16)fmaxf(acc[mt][nt][2] + bv.z, 0.f);
                pk[3] = (__bf16)fmaxf(acc[mt][nt][3] + bv.w, 0.f);
                *(bf16x4*)&hT[(size_t)n * CH + o] = pk;
            }
        }
    } else {
#pragma unroll
        for (int mt = 0; mt < 4; mt++) {
            int t0 = wy * 64 + mt * 16 + quad * 4;
#pragma unroll
            for (int nt = 0; nt < 4; nt++) {
                int n = nb * 128 + wx * 64 + nt * 16 + row16;
#pragma unroll
                for (int r = 0; r < 4; r++)
                    if (t0 + r < 49) atomicAdd(&Q[(size_t)(t0 + r) * ldq + n], acc[mt][nt][r]);
            }
        }
    }
}

// out[i,j] = sigmoid(b2 + sum_taps {Qfull | Qsingle | Qconst}), mirrored
__global__ void k_out(const float* __restrict__ Q, const float* __restrict__ Qs,
                      const float* __restrict__ Qc, const int* __restrict__ rank,
                      const int* __restrict__ counts, const float* b2,
                      float* __restrict__ outmaps) {
    __shared__ int rankL[256];
    __shared__ float QcL[52];
    int tid = threadIdx.x;
    rankL[tid] = rank[tid];
    if (tid < 49) QcL[tid] = Qc[tid];
    __syncthreads();
    int A = counts[0];
    int idx = blockIdx.x * 256 + tid;
    if (idx >= NPAIR) return;
    // invert full-256 triangular index
    float disc = 263169.0f - 8.0f * (float)idx;
    int i = (int)floorf((513.0f - sqrtf(fmaxf(disc, 0.f))) * 0.5f);
    i = min(255, max(0, i));
    while (i > 0 && tri_off(i) > idx) --i;
    while (tri_off(i + 1) <= idx) ++i;
    int j = i + (idx - tri_off(i));

    float acc = b2[0];
    for (int di = 0; di < 7; di++) {
        int p = i + di - 3;
        if ((unsigned)p > 255u) continue;
        for (int dj = 0; dj < 7; dj++) {
            int q = j + dj - 3;
            if ((unsigned)q > 255u) continue;
            int t = di * 7 + dj;
            int a = p, b = q;
            if (a > b) { a = q; b = p; }
            int ra = rankL[a], rb = rankL[b];
            if (ra >= 0) {
                if (rb >= 0) acc += Q[(size_t)t * LDQ + offA(ra, A) + (rb - ra)];
                else         acc += Qs[t * 256 + a];
            } else {
                if (rb >= 0) acc += Qs[t * 256 + b];
                else         acc += QcL[t];
            }
        }
    }
    float sg = 1.0f / (1.0f + expf(-acc));
    outmaps[i * 256 + j] = sg;
    outmaps[j * 256 + i] = sg;
}

// ---------------- launch ----------------

extern "C" void kernel_launch(void* const* d_in, const int* in_sizes, int n_in,
                              void* d_out, int out_size, void* d_ws, size_t ws_size,
                              hipStream_t stream) {
    const float* att    = (const float*)d_in[0];
    const float* pooled = (const float*)d_in[1];
    const int*   am     = (const int*)d_in[2];
    const float* lin1_w = (const float*)d_in[3];
    const float* lin1_b = (const float*)d_in[4];
    const float* cls_w  = (const float*)d_in[5];
    const float* cls_b  = (const float*)d_in[6];
    const float* c1w    = (const float*)d_in[7];
    const float* c1b    = (const float*)d_in[8];
    const float* c2w    = (const float*)d_in[9];
    const float* c2b    = (const float*)d_in[10];
    float* out = (float*)d_out;
    char*  ws  = (char*)d_ws;

    // workspace layout (~213.0 MB)
    __bf16* featT = (__bf16*)(ws);                    // PCAP*2048*2 = 133,169,152
    __bf16* hT    = (__bf16*)(ws + 133169152);        // PCAP*1024*2 =  66,584,576
    float*  Q     = (float*) (ws + 199753728);        // 49*LDQ*4    =   6,372,352
    __bf16* A1    = (__bf16*)(ws + 206126080);        // 1024*2048*2 =   4,194,304
    __bf16* K2    = (__bf16*)(ws + 210320384);        // 128*1024*2  =     262,144
    float*  z     = (float*) (ws + 210582528);        // 256*1024*4  =   1,048,576
    __bf16* absZ  = (__bf16*)(ws + 211631104);        // 256*1024*2  =     524,288
    __bf16* gT    = (__bf16*)(ws + 212155392);        // 256*1024*2  =     524,288
    float*  Qs    = (float*) (ws + 212679680);        // 49*256*4    =      50,176
    float*  Qc    = (float*) (ws + 212730112);        // 49*4 (pad 256)
    int*    pi    = (int*)   (ws + 212730368);        // 32896*4
    int*    pj    = (int*)   (ws + 212861952);        // 32896*4
    int*    rank  = (int*)   (ws + 212993536);        // 256*4
    int*    active= (int*)   (ws + 212994560);        // 256*4
    float*  hid   = (float*) (ws + 212995584);        // 1024*4
    int*    counts= (int*)   (ws + 212999680);        // 16*4

    k_scan  <<<1,    256, 0, stream>>>(am, rank, active, counts);
    k_pairs <<<129,  256, 0, stream>>>(active, counts, pi, pj);
    k_maskz <<<256,  256, 0, stream>>>(att, rank, z, absZ);
    k_cvtA  <<<1024, 256, 0, stream>>>(c1w, A1);
    k_prepK2<<<512,  256, 0, stream>>>(c2w, K2);
    k_qconst<<<49,   256, 0, stream>>>(c2w, c1b, Qc);
    k_zeroQ <<<1568, 256, 0, stream>>>(Q, Qs);
    k_gemv  <<<256,  256, 0, stream>>>(pooled, lin1_w, lin1_b, hid);   // hidden[1024]
    k_gemv  <<<500,  256, 0, stream>>>(hid, cls_w, cls_b, out);        // logits[2000]
    k_feat  <<<4112, 256, 0, stream>>>(z, pi, pj, counts, featT);

    // GEMM1: hT[n][o] = relu(A1 . featT[n]) over active pairs only
    gemm_bt <<<dim3(8, 257), 256, 0, stream>>>(A1, featT, K1, K1, K1, 0, 0,
                                               counts + 2, c1b, hT, nullptr);
    // gT[q][o] = relu(W_diff . |z_q| + b1)   (single-active columns)
    gemm_bt <<<dim3(8, 2),   256, 0, stream>>>(A1, absZ, CH, K1, CH, 0, 0,
                                               nullptr, c1b, gT, nullptr);
    // Qfull[t][n] = K2 . hT  (split-K 4x atomic)
    gemm_bt <<<dim3(4, 257), 256, 0, stream>>>(K2, hT, 256, CH, CH, 2, LDQ,
                                               counts + 2, nullptr, nullptr, Q);
    // Qsingle[t][q] = K2 . gT  (split-K 4x atomic)
    gemm_bt <<<dim3(4, 2),   256, 0, stream>>>(K2, gT, 256, CH, CH, 2, 256,
                                               nullptr, nullptr, nullptr, Qs);

    k_out   <<<129, 256, 0, stream>>>(Q, Qs, Qc, rank, counts, c2b, out + 2000);
}

// Round 4
// 195.886 us; speedup vs baseline: 2.0586x; 1.2719x over previous
//
#include <hip/hip_runtime.h>

typedef float  f4v    __attribute__((ext_vector_type(4)));
typedef __bf16 bf16x8 __attribute__((ext_vector_type(8)));
typedef __bf16 bf16x4 __attribute__((ext_vector_type(4)));

#define PCAP  32512   // max padded active-pair count (A<=254 -> P<=32385 -> pad128 -> 32512)
#define LDQ   32512
#define CH    1024
#define KK1   2048
#define NBF   508     // full-B 64-col tiles (PCAP/64); grid y = NBF+4 (single tiles)

__device__ __forceinline__ int offA(int r, int A) { return r * A - ((r * (r - 1)) >> 1); }

// ---------------- fused prep + feat kernel: blockIdx ranges ----------------
#define PB_FEAT   0       // 4064 blocks: featT rows n0=b*8 (self-scans mask)
#define PB_ABSZ   4064    // 256
#define PB_CVTA   4320    // 1024
#define PB_PREPK2 5344    // 512
#define PB_QCONST 5856    // 49
#define PB_ZEROQ  5905    // 1568
#define PB_SCAN   7473    // 1
#define PB_HID    7474    // 256
#define PB_TOTAL  7730

__global__ void k_prep(const float* __restrict__ att, const int* __restrict__ am,
                       const float* __restrict__ c1w, const float* __restrict__ c2w,
                       const float* __restrict__ c1b,
                       const float* __restrict__ pooled, const float* __restrict__ lin1_w,
                       const float* __restrict__ lin1_b,
                       int* rank, int* counts,
                       __bf16* featT, __bf16* absZ, __bf16* A1, __bf16* K2w,
                       float* Qc, float* Q, float* Qs, float* hid) {
    int b = blockIdx.x, t = threadIdx.x;

    if (b < PB_ABSZ) {
        // ---- feat: local ballot-scan of mask, decode pairs, build featT rows ----
        __shared__ int act[256];
        __shared__ int wred[4];
        __shared__ unsigned long long wm[4];
        int wave = t >> 6, lane = t & 63;
        int a = am[t];
        int sv = a;
#pragma unroll
        for (int d = 32; d; d >>= 1) sv += __shfl_down(sv, d);
        if (lane == 0) wred[wave] = sv;
        __syncthreads();
        int s = wred[0] + wred[1] + wred[2] + wred[3];
        int keep = (t != 0 && t != s && a != 0) ? 1 : 0;
        unsigned long long bm = __ballot(keep);
        if (lane == 0) wm[wave] = bm;
        __syncthreads();
        int base = 0, A = 0;
#pragma unroll
        for (int w = 0; w < 4; w++) {
            int pc = __popcll(wm[w]);
            if (w < wave) base += pc;
            A += pc;
        }
        if (keep) act[base + __popcll(bm & ((1ull << lane) - 1ull))] = t;
        __syncthreads();
        int P = (A * (A + 1)) >> 1;
        int Ppad = ((P + 127) >> 7) << 7;
        int n0 = b * 8;
        if (n0 >= Ppad) return;
        int c = (t & 127) * 8;
        bool ismul = (t >= 128);
        float fA = (float)(2 * A + 1);
        for (int q = 0; q < 8; q++) {
            int n = n0 + q;
            bf16x8 ov;
            if (n < P) {
                float disc = fmaxf(fA * fA - 8.0f * (float)n, 0.0f);
                int r = (int)floorf((fA - sqrtf(disc)) * 0.5f);
                r = min(A - 1, max(0, r));
                while (r > 0 && offA(r, A) > n) --r;
                while (r < A - 1 && offA(r + 1, A) <= n) ++r;
                int rj = r + (n - offA(r, A));
                int i = act[r], j = act[rj];
                const float* zi = &att[i * CH + c];
                const float* zj = &att[j * CH + c];
                float4 a0 = *(const float4*)zi, a1 = *(const float4*)(zi + 4);
                float4 b0 = *(const float4*)zj, b1 = *(const float4*)(zj + 4);
                float va[8] = {a0.x, a0.y, a0.z, a0.w, a1.x, a1.y, a1.z, a1.w};
                float vb[8] = {b0.x, b0.y, b0.z, b0.w, b1.x, b1.y, b1.z, b1.w};
#pragma unroll
                for (int r8 = 0; r8 < 8; r8++) {
                    float v = ismul ? (va[r8] * vb[r8]) : fabsf(va[r8] - vb[r8]);
                    ov[r8] = (__bf16)v;
                }
            } else {
#pragma unroll
                for (int r8 = 0; r8 < 8; r8++) ov[r8] = (__bf16)0.0f;
            }
            *(bf16x8*)&featT[(size_t)n * KK1 + t * 8] = ov;
        }
    } else if (b < PB_CVTA) {
        // ---- absZ row (recompute s via wave reduce) ----
        __shared__ int wred[4];
        int wave = t >> 6, lane = t & 63;
        int sv = am[t];
#pragma unroll
        for (int d = 32; d; d >>= 1) sv += __shfl_down(sv, d);
        if (lane == 0) wred[wave] = sv;
        __syncthreads();
        int s = wred[0] + wred[1] + wred[2] + wred[3];
        int l = b - PB_ABSZ;
        float m = (l != 0 && l != s && am[l] != 0) ? 1.f : 0.f;
        int c = t * 4;
        float4 v = *(const float4*)&att[l * CH + c];
        bf16x4 av;
        av[0] = (__bf16)(fabsf(v.x) * m); av[1] = (__bf16)(fabsf(v.y) * m);
        av[2] = (__bf16)(fabsf(v.z) * m); av[3] = (__bf16)(fabsf(v.w) * m);
        *(bf16x4*)&absZ[l * CH + c] = av;
    } else if (b < PB_PREPK2) {
        size_t e = ((size_t)(b - PB_CVTA) * 256 + t) * 8;
        float4 a = *(const float4*)&c1w[e];
        float4 v2 = *(const float4*)&c1w[e + 4];
        bf16x8 v;
        v[0] = (__bf16)a.x; v[1] = (__bf16)a.y; v[2] = (__bf16)a.z; v[3] = (__bf16)a.w;
        v[4] = (__bf16)v2.x; v[5] = (__bf16)v2.y; v[6] = (__bf16)v2.z; v[7] = (__bf16)v2.w;
        *(bf16x8*)&A1[e] = v;
    } else if (b < PB_QCONST) {
        int e = (b - PB_PREPK2) * 256 + t;   // 128*1024
        int tt = e >> 10, o = e & 1023;
        K2w[e] = (tt < 49) ? (__bf16)c2w[o * 49 + tt] : (__bf16)0.0f;
    } else if (b < PB_ZEROQ) {
        __shared__ float sh[256];
        int tap = b - PB_QCONST;
        float s = 0.f;
        for (int o = t; o < CH; o += 256) s += c2w[o * 49 + tap] * fmaxf(c1b[o], 0.f);
        sh[t] = s; __syncthreads();
        for (int d = 128; d; d >>= 1) { if (t < d) sh[t] += sh[t + d]; __syncthreads(); }
        if (t == 0) Qc[tap] = sh[0];
    } else if (b < PB_SCAN) {
        int idx = (b - PB_ZEROQ) * 256 + t;  // 401408 float4 = Q(398272) + Qs(3136)
        float4 zv = {0.f, 0.f, 0.f, 0.f};
        if (idx < 398272) ((float4*)Q)[idx] = zv;
        else ((float4*)Qs)[idx - 398272] = zv;
    } else if (b == PB_SCAN) {
        __shared__ int wred[4];
        __shared__ unsigned long long wm[4];
        int wave = t >> 6, lane = t & 63;
        int a = am[t];
        int sv = a;
#pragma unroll
        for (int d = 32; d; d >>= 1) sv += __shfl_down(sv, d);
        if (lane == 0) wred[wave] = sv;
        __syncthreads();
        int s = wred[0] + wred[1] + wred[2] + wred[3];
        int keep = (t != 0 && t != s && a != 0) ? 1 : 0;
        unsigned long long bm = __ballot(keep);
        if (lane == 0) wm[wave] = bm;
        __syncthreads();
        int base = 0, A = 0;
#pragma unroll
        for (int w = 0; w < 4; w++) {
            int pc = __popcll(wm[w]);
            if (w < wave) base += pc;
            A += pc;
        }
        int excl = base + __popcll(bm & ((1ull << lane) - 1ull));
        rank[t] = keep ? excl : -1;
        if (t == 0) {
            int P = (A * (A + 1)) >> 1;
            counts[0] = A; counts[1] = P; counts[2] = ((P + 127) >> 7) << 7;
        }
    } else {
        // ---- hid gemv: hid[o] = dot(pooled, lin1_w[o]) + lin1_b[o] ----
        int o = (b - PB_HID) * 4 + (t >> 6);
        int lane = t & 63;
        const float* row = lin1_w + (size_t)o * CH;
        float s = 0.f;
        for (int c = lane; c < CH; c += 64) s += pooled[c] * row[c];
        for (int d = 32; d; d >>= 1) s += __shfl_down(s, d);
        if (lane == 0) hid[o] = s + lin1_b[o];
    }
}

// ---------------- MFMA GEMM, 128M x 64N tiles, BK=32 ----------------
// grid (mbx, 512). nb<508: full B (64-col tiles, gated by counts[2]); nb>=508: single B.
// epi 0: O[n*CH+o] = bf16(relu(acc+bias[o])), arow=mb*128; mb==8 -> logits gemv blocks.
// epi 1: split-K (mb = k-chunk of 256, arow=0): atomicAdd Qp[t*ldq+n] for t<49.
__global__ __launch_bounds__(256) void gemm2(
        const __bf16* __restrict__ A, int lda,
        const __bf16* __restrict__ Bfull, int ldbf, int Kfull,
        const __bf16* __restrict__ Bsing, int ldbs, int Ksing,
        int epi, const int* __restrict__ counts, const float* __restrict__ bias,
        __bf16* __restrict__ Ofull, __bf16* __restrict__ Osing,
        float* __restrict__ Qfull, float* __restrict__ Qsing,
        const float* __restrict__ hid, const float* __restrict__ cls_w,
        const float* __restrict__ cls_b, float* __restrict__ logits) {
    int mb = blockIdx.x, nb = blockIdx.y;
    int tid = threadIdx.x, wave = tid >> 6, lane = tid & 63;

    if (epi == 0 && mb == 8) {
        // logits gemv: 500 working blocks x 4 rows
        if (nb >= 500) return;
        int o = nb * 4 + (tid >> 6);
        const float* row = cls_w + (size_t)o * CH;
        float s = 0.f;
        for (int c = lane; c < CH; c += 64) s += hid[c] * row[c];
        for (int d = 32; d; d >>= 1) s += __shfl_down(s, d);
        if (lane == 0) logits[o] = s + cls_b[o];
        return;
    }

    bool single = (nb >= NBF);
    const __bf16* Bp; int ldb, K, ncol0;
    if (!single) {
        if (nb * 64 >= counts[2]) return;
        Bp = Bfull + (size_t)nb * 64 * ldbf; ldb = ldbf; K = Kfull; ncol0 = nb * 64;
    } else {
        Bp = Bsing + (size_t)(nb - NBF) * 64 * ldbs; ldb = ldbs; K = Ksing;
        ncol0 = (nb - NBF) * 64;
    }
    int kbase, arow;
    if (epi == 1) { kbase = mb * 256; K = 256; arow = 0; }
    else          { kbase = 0; arow = mb * 128; }

    __shared__ __bf16 As[128][32];
    __shared__ __bf16 Bs[64][32];
    int rin = lane >> 2, cin = lane & 3;

    // staging: per wave 2 A-blocks (16 rows each) + 1 B-block (16 rows)
    const __bf16* srcA0 = A + (size_t)(arow + (wave * 2 + 0) * 16 + rin) * lda + kbase + cin * 8;
    const __bf16* srcA1 = A + (size_t)(arow + (wave * 2 + 1) * 16 + rin) * lda + kbase + cin * 8;
    const __bf16* srcB  = Bp + (size_t)(wave * 16 + rin) * ldb + kbase + cin * 8;
    __bf16* dstA0 = &As[(wave * 2 + 0) * 16][0];
    __bf16* dstA1 = &As[(wave * 2 + 1) * 16][0];
    __bf16* dstB  = &Bs[wave * 16][0];

    f4v acc[4][2] = {};
    int row16 = lane & 15, quad = lane >> 4;
    int wx = wave & 1, wy = wave >> 1;
    int kiters = K >> 5;

    for (int kt = 0; kt < kiters; ++kt) {
        __builtin_amdgcn_global_load_lds(
            (const __attribute__((address_space(1))) void*)srcA0,
            (__attribute__((address_space(3))) void*)dstA0, 16, 0, 0);
        __builtin_amdgcn_global_load_lds(
            (const __attribute__((address_space(1))) void*)srcA1,
            (__attribute__((address_space(3))) void*)dstA1, 16, 0, 0);
        __builtin_amdgcn_global_load_lds(
            (const __attribute__((address_space(1))) void*)srcB,
            (__attribute__((address_space(3))) void*)dstB, 16, 0, 0);
        srcA0 += 32; srcA1 += 32; srcB += 32;
        __syncthreads();
        bf16x8 a[4], b[2];
#pragma unroll
        for (int mt = 0; mt < 4; mt++) a[mt] = *(const bf16x8*)&As[wy * 64 + mt * 16 + row16][quad * 8];
#pragma unroll
        for (int nt = 0; nt < 2; nt++) b[nt] = *(const bf16x8*)&Bs[wx * 32 + nt * 16 + row16][quad * 8];
#pragma unroll
        for (int mt = 0; mt < 4; mt++)
#pragma unroll
            for (int nt = 0; nt < 2; nt++)
                acc[mt][nt] = __builtin_amdgcn_mfma_f32_16x16x32_bf16(a[mt], b[nt], acc[mt][nt], 0, 0, 0);
        __syncthreads();
    }

    if (epi == 0) {
        __bf16* Op = single ? Osing : Ofull;
#pragma unroll
        for (int mt = 0; mt < 4; mt++) {
            int o = arow + wy * 64 + mt * 16 + quad * 4;
            float4 bv = *(const float4*)&bias[o];
#pragma unroll
            for (int nt = 0; nt < 2; nt++) {
                int n = ncol0 + wx * 32 + nt * 16 + row16;
                bf16x4 pk;
                pk[0] = (__bf16)fmaxf(acc[mt][nt][0] + bv.x, 0.f);
                pk[1] = (__bf16)fmaxf(acc[mt][nt][1] + bv.y, 0.f);
                pk[2] = (__bf16)fmaxf(acc[mt][nt][2] + bv.z, 0.f);
                pk[3] = (__bf16)fmaxf(acc[mt][nt][3] + bv.w, 0.f);
                *(bf16x4*)&Op[(size_t)n * CH + o] = pk;
            }
        }
    } else {
        float* Qp = single ? Qsing : Qfull;
        int ldq = single ? 256 : LDQ;
#pragma unroll
        for (int mt = 0; mt < 4; mt++) {
            int t0 = wy * 64 + mt * 16 + quad * 4;
#pragma unroll
            for (int nt = 0; nt < 2; nt++) {
                int n = ncol0 + wx * 32 + nt * 16 + row16;
#pragma unroll
                for (int r = 0; r < 4; r++)
                    if (t0 + r < 49) atomicAdd(&Qp[(size_t)(t0 + r) * ldq + n], acc[mt][nt][r]);
            }
        }
    }
}

// ---------------- output: one thread per (i,j) ----------------
__global__ void k_out(const float* __restrict__ Q, const float* __restrict__ Qs,
                      const float* __restrict__ Qc, const int* __restrict__ rank,
                      const int* __restrict__ counts, const float* b2,
                      float* __restrict__ outmaps) {
    __shared__ int rankL[256];
    __shared__ float QcL[49];
    int t = threadIdx.x, i = blockIdx.x;
    rankL[t] = rank[t];
    if (t < 49) QcL[t] = Qc[t];
    __syncthreads();
    int A = counts[0];
    int j = t;
    float acc = b2[0];
#pragma unroll
    for (int di = 0; di < 7; di++) {
        int p = i + di - 3;
        if ((unsigned)p > 255u) continue;
#pragma unroll
        for (int dj = 0; dj < 7; dj++) {
            int q = j + dj - 3;
            if ((unsigned)q > 255u) continue;
            int tt = di * 7 + dj;
            int a = min(p, q), bb = max(p, q);
            int ra = rankL[a], rb = rankL[bb];
            float val;
            if (ra >= 0) val = (rb >= 0) ? Q[(size_t)tt * LDQ + offA(ra, A) + (rb - ra)]
                                         : Qs[tt * 256 + a];
            else         val = (rb >= 0) ? Qs[tt * 256 + bb] : QcL[tt];
            acc += val;
        }
    }
    outmaps[i * 256 + j] = 1.0f / (1.0f + expf(-acc));
}

// ---------------- launch ----------------

extern "C" void kernel_launch(void* const* d_in, const int* in_sizes, int n_in,
                              void* d_out, int out_size, void* d_ws, size_t ws_size,
                              hipStream_t stream) {
    const float* att    = (const float*)d_in[0];
    const float* pooled = (const float*)d_in[1];
    const int*   am     = (const int*)d_in[2];
    const float* lin1_w = (const float*)d_in[3];
    const float* lin1_b = (const float*)d_in[4];
    const float* cls_w  = (const float*)d_in[5];
    const float* cls_b  = (const float*)d_in[6];
    const float* c1w    = (const float*)d_in[7];
    const float* c1b    = (const float*)d_in[8];
    const float* c2w    = (const float*)d_in[9];
    const float* c2b    = (const float*)d_in[10];
    float* out = (float*)d_out;
    char*  ws  = (char*)d_ws;

    __bf16* featT = (__bf16*)(ws);                    // PCAP*2048*2 = 133,169,152
    __bf16* hT    = (__bf16*)(ws + 133169152);        // PCAP*1024*2 =  66,584,576
    float*  Q     = (float*) (ws + 199753728);        // 49*LDQ*4    =   6,372,352
    __bf16* A1    = (__bf16*)(ws + 206126080);        // 1024*2048*2 =   4,194,304
    __bf16* K2w   = (__bf16*)(ws + 210320384);        // 128*1024*2  =     262,144
    __bf16* absZ  = (__bf16*)(ws + 210582528);        // 256*1024*2  =     524,288
    __bf16* gT    = (__bf16*)(ws + 211106816);        // 256*1024*2  =     524,288
    float*  Qs    = (float*) (ws + 211631104);        // 49*256*4    =      50,176
    float*  Qc    = (float*) (ws + 211681280);        // 49*4 (pad 256)
    int*    rank  = (int*)   (ws + 211681536);        // 256*4 (pad 1024)
    float*  hid   = (float*) (ws + 211682560);        // 1024*4
    int*    counts= (int*)   (ws + 211686656);        // 16*4

    k_prep<<<PB_TOTAL, 256, 0, stream>>>(att, am, c1w, c2w, c1b, pooled, lin1_w, lin1_b,
                                         rank, counts, featT, absZ, A1, K2w, Qc, Q, Qs, hid);

    // GEMM1 (hT = relu(A1.featT+b1)) + single cols (gT = relu(Wd.|z|+b1)) + logits blocks
    gemm2<<<dim3(9, 512), 256, 0, stream>>>(A1, 2048, featT, 2048, 2048, absZ, 1024, 1024,
                                            0, counts, c1b, hT, gT, nullptr, nullptr,
                                            hid, cls_w, cls_b, out);
    // Q = K2.hT ; Qs = K2.gT  (split-K 4x atomic)
    gemm2<<<dim3(4, 512), 256, 0, stream>>>(K2w, 1024, hT, 1024, 256, gT, 1024, 256,
                                            1, counts, nullptr, nullptr, nullptr, Q, Qs,
                                            nullptr, nullptr, nullptr, nullptr);

    k_out<<<256, 256, 0, stream>>>(Q, Qs, Qc, rank, counts, c2b, out + 2000);
}

// Round 5
// 181.786 us; speedup vs baseline: 2.2182x; 1.0776x over previous
//
#include <hip/hip_runtime.h>

typedef float  f4v    __attribute__((ext_vector_type(4)));
typedef __bf16 bf16x8 __attribute__((ext_vector_type(8)));
typedef __bf16 bf16x4 __attribute__((ext_vector_type(4)));

#define PCAP  32512   // max padded active-pair count (A<=254 -> P<=32385 -> pad128 -> 32512)
#define LDQ   32512
#define CH    1024
#define KK1   2048
#define NBF   254     // full-B 128-col tiles (PCAP/128); grid y = NBF+2 (single tiles)

__device__ __forceinline__ int offA(int r, int A) { return r * A - ((r * (r - 1)) >> 1); }

// ---------------- fused prep + feat kernel: blockIdx ranges ----------------
#define PB_FEAT   0       // 4064 blocks: featT rows n0=b*8 (self-scans mask)
#define PB_ABSZ   4064    // 256
#define PB_CVTA   4320    // 1024
#define PB_PREPK2 5344    // 512
#define PB_QCONST 5856    // 49
#define PB_ZEROQ  5905    // 1568
#define PB_SCAN   7473    // 1
#define PB_HID    7474    // 256
#define PB_TOTAL  7730

__global__ void k_prep(const float* __restrict__ att, const int* __restrict__ am,
                       const float* __restrict__ c1w, const float* __restrict__ c2w,
                       const float* __restrict__ c1b,
                       const float* __restrict__ pooled, const float* __restrict__ lin1_w,
                       const float* __restrict__ lin1_b,
                       int* rank, int* counts,
                       __bf16* featT, __bf16* absZ, __bf16* A1, __bf16* K2w,
                       float* Qc, float* Q, float* Qs, float* hid) {
    int b = blockIdx.x, t = threadIdx.x;

    if (b < PB_ABSZ) {
        // ---- feat: local ballot-scan of mask, decode pairs, build featT rows ----
        __shared__ int act[256];
        __shared__ int wred[4];
        __shared__ unsigned long long wm[4];
        int wave = t >> 6, lane = t & 63;
        int a = am[t];
        int sv = a;
#pragma unroll
        for (int d = 32; d; d >>= 1) sv += __shfl_down(sv, d);
        if (lane == 0) wred[wave] = sv;
        __syncthreads();
        int s = wred[0] + wred[1] + wred[2] + wred[3];
        int keep = (t != 0 && t != s && a != 0) ? 1 : 0;
        unsigned long long bm = __ballot(keep);
        if (lane == 0) wm[wave] = bm;
        __syncthreads();
        int base = 0, A = 0;
#pragma unroll
        for (int w = 0; w < 4; w++) {
            int pc = __popcll(wm[w]);
            if (w < wave) base += pc;
            A += pc;
        }
        if (keep) act[base + __popcll(bm & ((1ull << lane) - 1ull))] = t;
        __syncthreads();
        int P = (A * (A + 1)) >> 1;
        int Ppad = ((P + 127) >> 7) << 7;
        int n0 = b * 8;
        if (n0 >= Ppad) return;
        int c = (t & 127) * 8;
        bool ismul = (t >= 128);
        float fA = (float)(2 * A + 1);
        for (int q = 0; q < 8; q++) {
            int n = n0 + q;
            bf16x8 ov;
            if (n < P) {
                float disc = fmaxf(fA * fA - 8.0f * (float)n, 0.0f);
                int r = (int)floorf((fA - sqrtf(disc)) * 0.5f);
                r = min(A - 1, max(0, r));
                while (r > 0 && offA(r, A) > n) --r;
                while (r < A - 1 && offA(r + 1, A) <= n) ++r;
                int rj = r + (n - offA(r, A));
                int i = act[r], j = act[rj];
                const float* zi = &att[i * CH + c];
                const float* zj = &att[j * CH + c];
                float4 a0 = *(const float4*)zi, a1 = *(const float4*)(zi + 4);
                float4 b0 = *(const float4*)zj, b1 = *(const float4*)(zj + 4);
                float va[8] = {a0.x, a0.y, a0.z, a0.w, a1.x, a1.y, a1.z, a1.w};
                float vb[8] = {b0.x, b0.y, b0.z, b0.w, b1.x, b1.y, b1.z, b1.w};
#pragma unroll
                for (int r8 = 0; r8 < 8; r8++) {
                    float v = ismul ? (va[r8] * vb[r8]) : fabsf(va[r8] - vb[r8]);
                    ov[r8] = (__bf16)v;
                }
            } else {
#pragma unroll
                for (int r8 = 0; r8 < 8; r8++) ov[r8] = (__bf16)0.0f;
            }
            *(bf16x8*)&featT[(size_t)n * KK1 + t * 8] = ov;
        }
    } else if (b < PB_CVTA) {
        // ---- absZ row (recompute s via wave reduce) ----
        __shared__ int wred[4];
        int wave = t >> 6, lane = t & 63;
        int sv = am[t];
#pragma unroll
        for (int d = 32; d; d >>= 1) sv += __shfl_down(sv, d);
        if (lane == 0) wred[wave] = sv;
        __syncthreads();
        int s = wred[0] + wred[1] + wred[2] + wred[3];
        int l = b - PB_ABSZ;
        float m = (l != 0 && l != s && am[l] != 0) ? 1.f : 0.f;
        int c = t * 4;
        float4 v = *(const float4*)&att[l * CH + c];
        bf16x4 av;
        av[0] = (__bf16)(fabsf(v.x) * m); av[1] = (__bf16)(fabsf(v.y) * m);
        av[2] = (__bf16)(fabsf(v.z) * m); av[3] = (__bf16)(fabsf(v.w) * m);
        *(bf16x4*)&absZ[l * CH + c] = av;
    } else if (b < PB_PREPK2) {
        size_t e = ((size_t)(b - PB_CVTA) * 256 + t) * 8;
        float4 a = *(const float4*)&c1w[e];
        float4 v2 = *(const float4*)&c1w[e + 4];
        bf16x8 v;
        v[0] = (__bf16)a.x; v[1] = (__bf16)a.y; v[2] = (__bf16)a.z; v[3] = (__bf16)a.w;
        v[4] = (__bf16)v2.x; v[5] = (__bf16)v2.y; v[6] = (__bf16)v2.z; v[7] = (__bf16)v2.w;
        *(bf16x8*)&A1[e] = v;
    } else if (b < PB_QCONST) {
        int e = (b - PB_PREPK2) * 256 + t;   // 128*1024
        int tt = e >> 10, o = e & 1023;
        K2w[e] = (tt < 49) ? (__bf16)c2w[o * 49 + tt] : (__bf16)0.0f;
    } else if (b < PB_ZEROQ) {
        __shared__ float sh[256];
        int tap = b - PB_QCONST;
        float s = 0.f;
        for (int o = t; o < CH; o += 256) s += c2w[o * 49 + tap] * fmaxf(c1b[o], 0.f);
        sh[t] = s; __syncthreads();
        for (int d = 128; d; d >>= 1) { if (t < d) sh[t] += sh[t + d]; __syncthreads(); }
        if (t == 0) Qc[tap] = sh[0];
    } else if (b < PB_SCAN) {
        int idx = (b - PB_ZEROQ) * 256 + t;  // 401408 float4 = Q(398272) + Qs(3136)
        float4 zv = {0.f, 0.f, 0.f, 0.f};
        if (idx < 398272) ((float4*)Q)[idx] = zv;
        else ((float4*)Qs)[idx - 398272] = zv;
    } else if (b == PB_SCAN) {
        __shared__ int wred[4];
        __shared__ unsigned long long wm[4];
        int wave = t >> 6, lane = t & 63;
        int a = am[t];
        int sv = a;
#pragma unroll
        for (int d = 32; d; d >>= 1) sv += __shfl_down(sv, d);
        if (lane == 0) wred[wave] = sv;
        __syncthreads();
        int s = wred[0] + wred[1] + wred[2] + wred[3];
        int keep = (t != 0 && t != s && a != 0) ? 1 : 0;
        unsigned long long bm = __ballot(keep);
        if (lane == 0) wm[wave] = bm;
        __syncthreads();
        int base = 0, A = 0;
#pragma unroll
        for (int w = 0; w < 4; w++) {
            int pc = __popcll(wm[w]);
            if (w < wave) base += pc;
            A += pc;
        }
        int excl = base + __popcll(bm & ((1ull << lane) - 1ull));
        rank[t] = keep ? excl : -1;
        if (t == 0) {
            int P = (A * (A + 1)) >> 1;
            counts[0] = A; counts[1] = P; counts[2] = ((P + 127) >> 7) << 7;
        }
    } else {
        // ---- hid gemv: hid[o] = dot(pooled, lin1_w[o]) + lin1_b[o] ----
        int o = (b - PB_HID) * 4 + (t >> 6);
        int lane = t & 63;
        const float* row = lin1_w + (size_t)o * CH;
        float s = 0.f;
        for (int c = lane; c < CH; c += 64) s += pooled[c] * row[c];
        for (int d = 32; d; d >>= 1) s += __shfl_down(s, d);
        if (lane == 0) hid[o] = s + lin1_b[o];
    }
}

// ---------------- MFMA GEMM, 128x128 tiles, BK=64, double-buffered LDS ----------------
// grid (mbx, 256). nb<254: full B (128-col tiles, gated by counts[2]); nb>=254: single B.
// epi 0: O[n*CH+o] = bf16(relu(acc+bias[o])), arow=mb*128; mb==8 -> logits gemv blocks.
// epi 1: split-K (mb = k-chunk of 256, arow=0): atomicAdd Qp[t*ldq+n] for t<49.
__global__ __launch_bounds__(256) void gemm2(
        const __bf16* __restrict__ A, int lda,
        const __bf16* __restrict__ Bfull, int ldbf, int Kfull,
        const __bf16* __restrict__ Bsing, int ldbs, int Ksing,
        int epi, const int* __restrict__ counts, const float* __restrict__ bias,
        __bf16* __restrict__ Ofull, __bf16* __restrict__ Osing,
        float* __restrict__ Qfull, float* __restrict__ Qsing,
        const float* __restrict__ hid, const float* __restrict__ cls_w,
        const float* __restrict__ cls_b, float* __restrict__ logits) {
    int mb = blockIdx.x, nb = blockIdx.y;
    int tid = threadIdx.x, wave = tid >> 6, lane = tid & 63;

    if (epi == 0 && mb == 8) {
        // logits gemv: 250 working blocks x 8 rows (2 per wave)
        if (nb >= 250) return;
#pragma unroll
        for (int rr = 0; rr < 2; rr++) {
            int o = nb * 8 + wave * 2 + rr;
            const float* row = cls_w + (size_t)o * CH;
            float s = 0.f;
            for (int c = lane; c < CH; c += 64) s += hid[c] * row[c];
            for (int d = 32; d; d >>= 1) s += __shfl_down(s, d);
            if (lane == 0) logits[o] = s + cls_b[o];
        }
        return;
    }

    bool single = (nb >= NBF);
    const __bf16* Bp; int ldb, K, ncol0;
    if (!single) {
        if (nb * 128 >= counts[2]) return;
        Bp = Bfull + (size_t)nb * 128 * ldbf; ldb = ldbf; K = Kfull; ncol0 = nb * 128;
    } else {
        Bp = Bsing + (size_t)(nb - NBF) * 128 * ldbs; ldb = ldbs; K = Ksing;
        ncol0 = (nb - NBF) * 128;
    }
    int kbase, arow;
    if (epi == 1) { kbase = mb * 256; K = 256; arow = 0; }
    else          { kbase = 0; arow = mb * 128; }

    __shared__ __bf16 As[2][128][64];
    __shared__ __bf16 Bs[2][128][64];

    // staging geometry: wave0 -> A rows 0-63, wave1 -> A rows 64-127,
    // wave2 -> B rows 0-63, wave3 -> B rows 64-127.
    // One instruction = 8 rows (8 lanes/row x 16B). XOR chunk swizzle:
    // physical chunk (lane&7) holds logical chunk (lane&7)^(lane>>3) of row lanerow.
    int isB = wave >> 1;
    int rowbase = (wave & 1) * 64;
    int lanerow = lane >> 3;                       // 0..7
    int lanechunk = ((lane & 7) ^ lanerow) * 8;    // element offset of logical chunk
    const __bf16* G = isB ? Bp : (A + (size_t)arow * lda);
    int ldg = isB ? ldb : lda;
    const __bf16* srcbase = G + (size_t)(rowbase + lanerow) * ldg + kbase + lanechunk;

    f4v acc[4][4] = {};
    int row16 = lane & 15, quad = lane >> 4;
    int wx = wave & 1, wy = wave >> 1;
    int kiters = K >> 6;

#define STAGE(k, bsel)                                                          \
    {                                                                           \
        const __bf16* sP = srcbase + (k) * 64;                                  \
        _Pragma("unroll")                                                       \
        for (int q = 0; q < 8; q++) {                                           \
            __bf16* dP = isB ? &Bs[bsel][rowbase + q * 8][0]                    \
                             : &As[bsel][rowbase + q * 8][0];                   \
            __builtin_amdgcn_global_load_lds(                                   \
                (const __attribute__((address_space(1))) void*)(sP + (size_t)q * 8 * ldg), \
                (__attribute__((address_space(3))) void*)dP, 16, 0, 0);         \
        }                                                                       \
    }

    STAGE(0, 0);
    for (int kt = 0; kt < kiters; ++kt) {
        int cur = kt & 1;
        if (kt + 1 < kiters) {
            STAGE(kt + 1, cur ^ 1);
            __builtin_amdgcn_s_waitcnt(0xF78);   // vmcnt(8): old batch done, new in flight
        } else {
            __builtin_amdgcn_s_waitcnt(0xF70);   // vmcnt(0)
        }
        __builtin_amdgcn_s_barrier();
#pragma unroll
        for (int ks = 0; ks < 2; ks++) {
            bf16x8 a[4], b[4];
            int col = ((ks * 4 + quad) ^ (row16 & 7)) * 8;
#pragma unroll
            for (int mt = 0; mt < 4; mt++)
                a[mt] = *(const bf16x8*)&As[cur][wy * 64 + mt * 16 + row16][col];
#pragma unroll
            for (int nt = 0; nt < 4; nt++)
                b[nt] = *(const bf16x8*)&Bs[cur][wx * 64 + nt * 16 + row16][col];
#pragma unroll
            for (int mt = 0; mt < 4; mt++)
#pragma unroll
                for (int nt = 0; nt < 4; nt++)
                    acc[mt][nt] = __builtin_amdgcn_mfma_f32_16x16x32_bf16(a[mt], b[nt], acc[mt][nt], 0, 0, 0);
        }
        __builtin_amdgcn_s_barrier();
    }
#undef STAGE

    if (epi == 0) {
        __bf16* Op = single ? Osing : Ofull;
#pragma unroll
        for (int mt = 0; mt < 4; mt++) {
            int o = arow + wy * 64 + mt * 16 + quad * 4;
            float4 bv = *(const float4*)&bias[o];
#pragma unroll
            for (int nt = 0; nt < 4; nt++) {
                int n = ncol0 + wx * 64 + nt * 16 + row16;
                bf16x4 pk;
                pk[0] = (__bf16)fmaxf(acc[mt][nt][0] + bv.x, 0.f);
                pk[1] = (__bf16)fmaxf(acc[mt][nt][1] + bv.y, 0.f);
                pk[2] = (__bf16)fmaxf(acc[mt][nt][2] + bv.z, 0.f);
                pk[3] = (__bf16)fmaxf(acc[mt][nt][3] + bv.w, 0.f);
                *(bf16x4*)&Op[(size_t)n * CH + o] = pk;
            }
        }
    } else {
        float* Qp = single ? Qsing : Qfull;
        int ldq = single ? 256 : LDQ;
#pragma unroll
        for (int mt = 0; mt < 4; mt++) {
            int t0 = wy * 64 + mt * 16 + quad * 4;
#pragma unroll
            for (int nt = 0; nt < 4; nt++) {
                int n = ncol0 + wx * 64 + nt * 16 + row16;
#pragma unroll
                for (int r = 0; r < 4; r++)
                    if (t0 + r < 49) atomicAdd(&Qp[(size_t)(t0 + r) * ldq + n], acc[mt][nt][r]);
            }
        }
    }
}

// ---------------- output: one thread per (i,j) ----------------
__global__ void k_out(const float* __restrict__ Q, const float* __restrict__ Qs,
                      const float* __restrict__ Qc, const int* __restrict__ rank,
                      const int* __restrict__ counts, const float* b2,
                      float* __restrict__ outmaps) {
    __shared__ int rankL[256];
    __shared__ float QcL[49];
    int t = threadIdx.x, i = blockIdx.x;
    rankL[t] = rank[t];
    if (t < 49) QcL[t] = Qc[t];
    __syncthreads();
    int A = counts[0];
    int j = t;
    float acc = b2[0];
#pragma unroll
    for (int di = 0; di < 7; di++) {
        int p = i + di - 3;
        if ((unsigned)p > 255u) continue;
#pragma unroll
        for (int dj = 0; dj < 7; dj++) {
            int q = j + dj - 3;
            if ((unsigned)q > 255u) continue;
            int tt = di * 7 + dj;
            int a = min(p, q), bb = max(p, q);
            int ra = rankL[a], rb = rankL[bb];
            float val;
            if (ra >= 0) val = (rb >= 0) ? Q[(size_t)tt * LDQ + offA(ra, A) + (rb - ra)]
                                         : Qs[tt * 256 + a];
            else         val = (rb >= 0) ? Qs[tt * 256 + bb] : QcL[tt];
            acc += val;
        }
    }
    outmaps[i * 256 + j] = 1.0f / (1.0f + expf(-acc));
}

// ---------------- launch ----------------

extern "C" void kernel_launch(void* const* d_in, const int* in_sizes, int n_in,
                              void* d_out, int out_size, void* d_ws, size_t ws_size,
                              hipStream_t stream) {
    const float* att    = (const float*)d_in[0];
    const float* pooled = (const float*)d_in[1];
    const int*   am     = (const int*)d_in[2];
    const float* lin1_w = (const float*)d_in[3];
    const float* lin1_b = (const float*)d_in[4];
    const float* cls_w  = (const float*)d_in[5];
    const float* cls_b  = (const float*)d_in[6];
    const float* c1w    = (const float*)d_in[7];
    const float* c1b    = (const float*)d_in[8];
    const float* c2w    = (const float*)d_in[9];
    const float* c2b    = (const float*)d_in[10];
    float* out = (float*)d_out;
    char*  ws  = (char*)d_ws;

    __bf16* featT = (__bf16*)(ws);                    // PCAP*2048*2 = 133,169,152
    __bf16* hT    = (__bf16*)(ws + 133169152);        // PCAP*1024*2 =  66,584,576
    float*  Q     = (float*) (ws + 199753728);        // 49*LDQ*4    =   6,372,352
    __bf16* A1    = (__bf16*)(ws + 206126080);        // 1024*2048*2 =   4,194,304
    __bf16* K2w   = (__bf16*)(ws + 210320384);        // 128*1024*2  =     262,144
    __bf16* absZ  = (__bf16*)(ws + 210582528);        // 256*1024*2  =     524,288
    __bf16* gT    = (__bf16*)(ws + 211106816);        // 256*1024*2  =     524,288
    float*  Qs    = (float*) (ws + 211631104);        // 49*256*4    =      50,176
    float*  Qc    = (float*) (ws + 211681280);        // 49*4 (pad 256)
    int*    rank  = (int*)   (ws + 211681536);        // 256*4 (pad 1024)
    float*  hid   = (float*) (ws + 211682560);        // 1024*4
    int*    counts= (int*)   (ws + 211686656);        // 16*4

    k_prep<<<PB_TOTAL, 256, 0, stream>>>(att, am, c1w, c2w, c1b, pooled, lin1_w, lin1_b,
                                         rank, counts, featT, absZ, A1, K2w, Qc, Q, Qs, hid);

    // GEMM1 (hT = relu(A1.featT+b1)) + single cols (gT = relu(Wd.|z|+b1)) + logits blocks
    gemm2<<<dim3(9, 256), 256, 0, stream>>>(A1, 2048, featT, 2048, 2048, absZ, 1024, 1024,
                                            0, counts, c1b, hT, gT, nullptr, nullptr,
                                            hid, cls_w, cls_b, out);
    // Q = K2.hT ; Qs = K2.gT  (split-K 4x atomic, K-chunks of 256)
    gemm2<<<dim3(4, 256), 256, 0, stream>>>(K2w, 1024, hT, 1024, 256, gT, 1024, 256,
                                            1, counts, nullptr, nullptr, nullptr, Q, Qs,
                                            nullptr, nullptr, nullptr, nullptr);

    k_out<<<256, 256, 0, stream>>>(Q, Qs, Qc, rank, counts, c2b, out + 2000);
}